// Round 18
// baseline (187.188 us; speedup 1.0000x reference)
//
#include <hip/hip_runtime.h>
#include <hip/hip_bf16.h>

#define T_DIM 800
#define B_DIM 32
#define V_DIM 1024
#define S_DIM 100
#define L2E  1.4426950408889634f
#define LN2  0.6931471805599453f

#define NPREP 1600               /* blocks: b = bid/50, chunk = bid%50, 16 rows each */
#define EOFF 4096                /* E starts at ws + EOFF floats (16 KB) */
#define EROW 128                 /* padded E row: 104 used slots (512 B) */
#define BROWS 801                /* per-batch row stride (row 800 = overrun pad) */

// ws layout (32-bit slots):
// [0]        : uint cnt   — rec completions          (memset each call)
// [1..33)    : uint bcnt[32] — per-batch prep counts (memset each call)
// [33..1633) : float partials[1600]
// [1633..1665): float nlls[32]
// [EOFF..)   : E[32][801][128] emission matrix (13.1 MB)

__device__ __forceinline__ float dpp_shr1_f(float x) {
    return __int_as_float(__builtin_amdgcn_update_dpp(
        0, __float_as_int(x), 0x138, 0xF, 0xF, false));
}
__device__ __forceinline__ int dpp_shr1_i(int x) {
    return __builtin_amdgcn_update_dpp(0, x, 0x138, 0xF, 0xF, false);
}
__device__ __forceinline__ float rl50(float x) {
    return __int_as_float(__builtin_amdgcn_readlane(__float_as_int(x), 50));
}
__device__ __forceinline__ void gl16(const float* g, float* lds_dst) {
    __builtin_amdgcn_global_load_lds(
        (const __attribute__((address_space(1))) unsigned int*)g,
        (__attribute__((address_space(3))) unsigned int*)lds_dst,
        16, 0, 0);
}

extern "C" __global__ void __launch_bounds__(256)
ctc_fused(const float* __restrict__ lp,
          const int* __restrict__ tgt,
          const int* __restrict__ ilen,
          const int* __restrict__ tlen,
          float* __restrict__ ws,
          float* __restrict__ out)
{
    __shared__ float smem[8192];        // 32 KB: prep row-buffers, then rec bufA/B
    __shared__ float red[4];
    __shared__ int role;
    unsigned int* cnt  = (unsigned int*)ws;
    unsigned int* bcnt = (unsigned int*)ws + 1;
    float* partials = ws + 33;
    float* nlls = ws + 1633;
    float* Eall = ws + EOFF;
    const int bid = blockIdx.x;
    const int tid = threadIdx.x;
    const int w = tid >> 6, j = tid & 63;
    const int b = bid / 50;             // batch-major: early batches finish early
    const int chunk = bid - b * 50;
    const int* tg = tgt + b * S_DIM;
    float* E = Eall + (size_t)b * BROWS * EROW;

    // ================= prep phase (R15/16-validated body) =================
    {
        const int t0 = chunk * 16 + w * 4;
        float* rb = smem + w * 2048;    // per-wave [2][1024]
        int c1 = 0, c2 = 0;
        if (j <= 49) { int2 t2 = ((const int2*)tg)[j]; c1 = t2.x; c2 = t2.y; }
        float s = 0.0f;
        #pragma unroll
        for (int i = 0; i < 4; ++i) {
            const int t = t0 + i;
            const float4* src = (const float4*)(lp + ((size_t)t * B_DIM + b) * V_DIM);
            float4 va = src[j], vb = src[j + 64], vc = src[j + 128], vd = src[j + 192];
            s += ((va.x + va.y) + (va.z + va.w)) + ((vb.x + vb.y) + (vb.z + vb.w))
               + ((vc.x + vc.y) + (vc.z + vc.w)) + ((vd.x + vd.y) + (vd.z + vd.w));
            float* rw = rb + (i & 1) * 1024;
            ((float4*)rw)[j] = va; ((float4*)rw)[j + 64] = vb;
            ((float4*)rw)[j + 128] = vc; ((float4*)rw)[j + 192] = vd;
            float a, c;
            if (j <= 49)      { a = __builtin_amdgcn_exp2f(rw[c1] * L2E);
                                c = __builtin_amdgcn_exp2f(rw[c2] * L2E); }
            else if (j == 50) { float ebv = __builtin_amdgcn_exp2f(rw[0] * L2E);
                                a = ebv; c = ebv; }
            else              { a = 0.0f; c = 0.0f; }
            ((float2*)(E + (size_t)t * EROW))[j] = make_float2(a, c);
        }
        for (int off = 32; off; off >>= 1) s += __shfl_down(s, off, 64);
        if (j == 0) red[w] = s;
        __syncthreads();                 // all waves' E stores drained (vmcnt0+bar)
        if (tid == 0) {
            partials[bid] = (red[0] + red[1]) + (red[2] + red[3]);
            __threadfence();             // agent release: E chunk + partial
            unsigned old = __hip_atomic_fetch_add(&bcnt[b], 1u, __ATOMIC_ACQ_REL,
                                                  __HIP_MEMORY_SCOPE_AGENT);
            role = (old == 49) ? 1 : 0;  // last finisher becomes rec for batch b
        }
        __syncthreads();
        if (!role) return;
        __threadfence();                 // acquire on ALL waves before reading E
    }

    // ================= rec role (R16/R17-validated, zero spins) =================
    float* bufA = smem;                  // 16 KB (prep done with smem)
    float* bufB = smem + 4096;           // 16 KB
    const int l = j;
    const int len = ilen[b];
    const int tl  = tlen[b];
    const int steps = len - 1;           // t = 1..len-1 ; len in [400,800]
    const int nfull = steps >> 5;
    const int nst   = steps & 31;
    const int N     = nfull + (nst ? 1 : 0);

#define WAIT0 do { \
    asm volatile("s_waitcnt vmcnt(0)" ::: "memory"); \
    __builtin_amdgcn_sched_barrier(0); \
} while (0)

    if (w != 0) {
        // ---------- stager waves 1..3 (split the 16 row-pair DMAs) ----------
        #pragma unroll 1
        for (int k = 0; k < N; ++k) {
            const int tb_ = 1 + 32 * k;
            float* bp_ = (k & 1) ? bufB : bufA;
            for (int g = w - 1; g < 16; g += 3) {
                gl16(E + (size_t)(tb_ + 2 * g) * EROW + 4 * l, bp_ + g * 256);
            }
            WAIT0;
            __builtin_amdgcn_s_barrier();     // bar#k: buf(k) ready
        }
        return;                               // N barriers
    }

    // ---------- consumer wave ----------
    float cs1f = 0, cs3f = 0;
    if (l <= 49) {
        int v1 = tg[2 * l];
        int vp = (l >= 1) ? tg[2 * l - 1] : -1;
        cs1f = (v1 != vp) ? 1.0f : 0.0f;
        int v3 = tg[2 * l + 1];
        cs3f = (v3 != v1) ? 1.0f : 0.0f;
    }

    float p0 = 0, p1 = 0, p2 = 0, p3 = 0;
    float qv = 0, sff = 0, sfg = 0;
    int   el = 0, eLp = 0;
    {
        float2 q0 = ((const float2*)E)[l];   // row 0, visible post-acquire
        float eb0 = rl50(q0.x);
        p0 = (l == 0) ? eb0  : 0.0f;
        p1 = (l == 0) ? q0.x : 0.0f;
    }

    float2 ga0, ga1, ga2, ga3, gb0, gb1, gb2, gb3;

#define PREF_(BUF, G, R0, R1, R2, R3) do { \
    const float2* bp_ = (const float2*)(BUF); \
    R0 = bp_[(4 * (G) + 0) * 64 + l]; \
    R1 = bp_[(4 * (G) + 1) * 64 + l]; \
    R2 = bp_[(4 * (G) + 2) * 64 + l]; \
    R3 = bp_[(4 * (G) + 3) * 64 + l]; \
} while (0)

#define BD do { \
    float mz_ = fmaxf(fmaxf(p0, p1), fmaxf(p2, p3)); \
    int dead_ = (mz_ == 0.0f) ? 1 : 0; \
    int er_ = (int)((__float_as_uint(mz_) >> 23) & 255u); \
    unsigned fld_ = dead_ ? 127u : (unsigned)(254 - er_); \
    float sc_ = __uint_as_float(fld_ << 23); \
    p0 *= sc_; p1 *= sc_; p2 *= sc_; p3 *= sc_; \
    el += dead_ ? 0 : (er_ - 127); \
    int e1s_ = dpp_shr1_i(el); \
    int elA_ = dead_ ? e1s_ : el; \
    int e2s_ = dpp_shr1_i(elA_); \
    int elB_ = dead_ ? e2s_ : el; \
    int e3s_ = dpp_shr1_i(elB_); \
    int d1_ = e3s_ - elB_; d1_ = d1_ < -120 ? -120 : (d1_ > 120 ? 120 : d1_); \
    int d2_ = eLp  - elB_; d2_ = d2_ < -120 ? -120 : (d2_ > 120 ? 120 : d2_); \
    sfg = (l == 0) ? 0.0f : __uint_as_float((unsigned)(d1_ + 127) << 23); \
    sff = (l == 0) ? 0.0f : __uint_as_float((unsigned)(d2_ + 127) << 23); \
    el = elB_; eLp = e3s_; \
} while (0)

#define ST(SF, Q, EBS) do { \
    float h3_ = qv * (SF); \
    float vown_ = fmaf(cs3f, p1, p2 + p3); \
    float n3_ = vown_ * (Q).y; \
    float n0_ = (p0 + h3_) * (EBS); \
    float n1_ = fmaf(cs1f, h3_, p0 + p1) * (Q).x; \
    float n2_ = (p1 + p2) * (EBS); \
    qv = dpp_shr1_f(n3_); \
    p0 = n0_; p1 = n1_; p2 = n2_; p3 = n3_; \
} while (0)

#define GRP_(R0, R1, R2, R3) do { \
    BD; \
    ST(sff, R0, rl50(R0.x)); \
    ST(sfg, R1, rl50(R1.x)); \
    ST(sfg, R2, rl50(R2.x)); \
    ST(sfg, R3, rl50(R3.x)); \
} while (0)

#define GRPT_(R0, R1, R2, R3, BASE) do { \
    if ((BASE) < nst) { \
        BD; \
        ST(sff, R0, rl50(R0.x)); \
        if ((BASE) + 1 < nst) ST(sfg, R1, rl50(R1.x)); \
        if ((BASE) + 2 < nst) ST(sfg, R2, rl50(R2.x)); \
        if ((BASE) + 3 < nst) ST(sfg, R3, rl50(R3.x)); \
    } \
} while (0)

#define CONS_FULL(BUF) do { \
    PREF_(BUF, 0, ga0, ga1, ga2, ga3); \
    PREF_(BUF, 1, gb0, gb1, gb2, gb3); GRP_(ga0, ga1, ga2, ga3); \
    PREF_(BUF, 2, ga0, ga1, ga2, ga3); GRP_(gb0, gb1, gb2, gb3); \
    PREF_(BUF, 3, gb0, gb1, gb2, gb3); GRP_(ga0, ga1, ga2, ga3); \
    PREF_(BUF, 4, ga0, ga1, ga2, ga3); GRP_(gb0, gb1, gb2, gb3); \
    PREF_(BUF, 5, gb0, gb1, gb2, gb3); GRP_(ga0, ga1, ga2, ga3); \
    PREF_(BUF, 6, ga0, ga1, ga2, ga3); GRP_(gb0, gb1, gb2, gb3); \
    PREF_(BUF, 7, gb0, gb1, gb2, gb3); GRP_(ga0, ga1, ga2, ga3); \
    GRP_(gb0, gb1, gb2, gb3); \
} while (0)

#define CONS_TAIL(BUF) do { \
    PREF_(BUF, 0, ga0, ga1, ga2, ga3); \
    PREF_(BUF, 1, gb0, gb1, gb2, gb3); GRPT_(ga0, ga1, ga2, ga3, 0); \
    PREF_(BUF, 2, ga0, ga1, ga2, ga3); GRPT_(gb0, gb1, gb2, gb3, 4); \
    PREF_(BUF, 3, gb0, gb1, gb2, gb3); GRPT_(ga0, ga1, ga2, ga3, 8); \
    PREF_(BUF, 4, ga0, ga1, ga2, ga3); GRPT_(gb0, gb1, gb2, gb3, 12); \
    PREF_(BUF, 5, gb0, gb1, gb2, gb3); GRPT_(ga0, ga1, ga2, ga3, 16); \
    PREF_(BUF, 6, ga0, ga1, ga2, ga3); GRPT_(gb0, gb1, gb2, gb3, 20); \
    PREF_(BUF, 7, gb0, gb1, gb2, gb3); GRPT_(ga0, ga1, ga2, ga3, 24); \
    GRPT_(gb0, gb1, gb2, gb3, 28); \
} while (0)

    __builtin_amdgcn_s_barrier();             // bar#0: buf(0) ready
    #pragma unroll 1
    for (int k = 0; k + 1 < N; ++k) {
        const float* cur = (k & 1) ? bufB : bufA;
        CONS_FULL(cur);
        __builtin_amdgcn_s_barrier();         // bar#k+1
    }
    {
        const float* cur = ((N - 1) & 1) ? bufB : bufA;
        if (nst) { CONS_TAIL(cur); } else { CONS_FULL(cur); }
    }

    // extract alpha[2*tl] and alpha[2*tl-1]  (log2 domain via p, el)
    int idx = 2 * tl;
    int lanehi = idx >> 2, rhi = idx & 3;
    int lanelo = (idx - 1) >> 2, rlo = (idx - 1) & 3;
    float q0 = __shfl(p0, lanehi, 64), q1 = __shfl(p1, lanehi, 64);
    float q2 = __shfl(p2, lanehi, 64), q3 = __shfl(p3, lanehi, 64);
    int   eh = __shfl(el, lanehi, 64);
    float ph = (rhi == 0) ? q0 : (rhi == 1) ? q1 : (rhi == 2) ? q2 : q3;
    float g0 = __shfl(p0, lanelo, 64), g1 = __shfl(p1, lanelo, 64);
    float g2 = __shfl(p2, lanelo, 64), g3 = __shfl(p3, lanelo, 64);
    int   eo = __shfl(el, lanelo, 64);
    float pl = (rlo == 0) ? g0 : (rlo == 1) ? g1 : (rlo == 2) ? g2 : g3;
    float vhi = (ph > 0.0f) ? __builtin_amdgcn_logf(ph) + (float)eh : -3.0e9f;
    float vlo = (pl > 0.0f) ? __builtin_amdgcn_logf(pl) + (float)eo : -3.0e9f;
    float m = fmaxf(vhi, vlo);
    float d = fminf(vhi, vlo) - m;
    float ll2 = m + __builtin_amdgcn_logf(1.0f + __builtin_amdgcn_exp2f(d));
    float nll = -ll2 * LN2;
    if (!(nll < 1e9f)) nll = 0.0f;            // zero_infinity (NaN-safe)

    int last = 0;
    if (l == 0) {
        nlls[b] = nll;
        __threadfence();
        unsigned old = __hip_atomic_fetch_add(cnt, 1u, __ATOMIC_ACQ_REL,
                                              __HIP_MEMORY_SCOPE_AGENT);
        last = (old == B_DIM - 1) ? 1 : 0;
    }
    last = __shfl(last, 0, 64);
    if (last) {
        // all recs done => each acquired its batch's 50 partials => transitive
        float ps = 0.0f;
        for (int i = l; i < NPREP; i += 64) ps += partials[i];
        for (int off = 32; off; off >>= 1) ps += __shfl_down(ps, off, 64);
        float cs = 0.0f;
        if (l < B_DIM) cs = nlls[l] / (float)tlen[l];
        for (int off = 32; off; off >>= 1) cs += __shfl_down(cs, off, 64);
        if (l == 0) {
            float smooth = -ps / (float)((long long)T_DIM * B_DIM * V_DIM);
            float ctc = cs / (float)B_DIM;
            out[0] = 0.9f * ctc + 0.1f * smooth;
        }
    }
}

extern "C" void kernel_launch(void* const* d_in, const int* in_sizes, int n_in,
                              void* d_out, int out_size, void* d_ws, size_t ws_size,
                              hipStream_t stream) {
    const float* lp  = (const float*)d_in[0];
    const int* tgt   = (const int*)d_in[1];
    const int* ilen  = (const int*)d_in[2];
    const int* tlen  = (const int*)d_in[3];
    float* out = (float*)d_out;
    float* ws  = (float*)d_ws;
    // zero cnt + bcnt[32] (132 bytes)
    hipMemsetAsync(d_ws, 0, 132, stream);
    ctc_fused<<<NPREP, 256, 0, stream>>>(lp, tgt, ilen, tlen, ws, out);
}

// Round 19
// 63.673 us; speedup vs baseline: 2.9398x; 2.9398x over previous
//
#include <hip/hip_runtime.h>
#include <hip/hip_bf16.h>

#define T_DIM 800
#define B_DIM 32
#define V_DIM 1024
#define S_DIM 100
#define L2E  1.4426950408889634f
#define LN2  0.6931471805599453f

#define NB1  1600                /* K1 blocks: 16 rows each */
#define EOFF 4096                /* E starts at ws + EOFF floats (16 KB) */
#define EROW 128                 /* padded E row: 104 used slots (512 B) */
#define BROWS 801                /* per-batch row stride (row 800 = overrun pad) */

// ws layout (32-bit slots):
// [0]                  : uint counter (zeroed by ctc_prep block 0 each call)
// [1 .. 1+NB1)         : float partial sums (smoothing reduction)
// [1+NB1 .. 1+NB1+32)  : float per-batch nll
// [EOFF ..)            : E[32][801][128] emission matrix (13.1 MB)

__device__ __forceinline__ float dpp_shr1_f(float x) {
    return __int_as_float(__builtin_amdgcn_update_dpp(
        0, __float_as_int(x), 0x138, 0xF, 0xF, false));
}
__device__ __forceinline__ int dpp_shr1_i(int x) {
    return __builtin_amdgcn_update_dpp(0, x, 0x138, 0xF, 0xF, false);
}
__device__ __forceinline__ float rl50(float x) {
    return __int_as_float(__builtin_amdgcn_readlane(__float_as_int(x), 50));
}
__device__ __forceinline__ void gl16(const float* g, float* lds_dst) {
    __builtin_amdgcn_global_load_lds(
        (const __attribute__((address_space(1))) unsigned int*)g,
        (__attribute__((address_space(3))) unsigned int*)lds_dst,
        16, 0, 0);
}

// ========== K1: smoothing-reduction + E build ==========
// vs R16: single 4KB LDS buffer/wave (16KB/block -> ~8 blocks/CU, was 4) and
// explicit 1-row-ahead load pipeline in named registers so each row's 4
// global loads are issued a full row early. In-wave DS ordering makes the
// single buffer safe (row i gather reads precede row i+1 writes in program
// order). No agent fences anywhere (R17/R18 lesson: each one = L2 flush).
extern "C" __global__ void __launch_bounds__(256)
ctc_prep(const float* __restrict__ lp,
         const int* __restrict__ tgt,
         float* __restrict__ ws)
{
    __shared__ float rb[4][V_DIM];      // 16 KB: per-wave single buffer
    __shared__ float red[4];
    float* E = ws + EOFF;
    float* partials = ws + 1;
    const int bid = blockIdx.x;
    const int tid = threadIdx.x;
    const int w = tid >> 6, j = tid & 63;
    const int b  = bid / 50;            // 50 blocks per batch
    const int t0 = (bid - b * 50) * 16 + w * 4;
    const int* tg = tgt + b * S_DIM;

    if (bid == 0 && tid == 0) ((unsigned int*)ws)[0] = 0;   // zero rec counter

    int c1 = 0, c2 = 0;
    if (j <= 49) { int2 t2 = ((const int2*)tg)[j]; c1 = t2.x; c2 = t2.y; }

    const float* base = lp + ((size_t)t0 * B_DIM + b) * V_DIM;
    const size_t RSTRIDE = (size_t)B_DIM * V_DIM;

    // preload row 0 into named registers
    const float4* s0 = (const float4*)base;
    float4 A = s0[j], Bv = s0[j + 64], C = s0[j + 128], D = s0[j + 192];

    float s = 0.0f;
    #pragma unroll
    for (int i = 0; i < 4; ++i) {
        float4 A2 = A, B2 = Bv, C2 = C, D2 = D;
        if (i < 3) {                     // issue next row's loads early
            const float4* sn = (const float4*)(base + (size_t)(i + 1) * RSTRIDE);
            A2 = sn[j]; B2 = sn[j + 64]; C2 = sn[j + 128]; D2 = sn[j + 192];
        }
        s += ((A.x + A.y) + (A.z + A.w)) + ((Bv.x + Bv.y) + (Bv.z + Bv.w))
           + ((C.x + C.y) + (C.z + C.w)) + ((D.x + D.y) + (D.z + D.w));
        float* rw = rb[w];
        ((float4*)rw)[j] = A; ((float4*)rw)[j + 64] = Bv;
        ((float4*)rw)[j + 128] = C; ((float4*)rw)[j + 192] = D;
        float a, c;
        if (j <= 49)      { a = __builtin_amdgcn_exp2f(rw[c1] * L2E);
                            c = __builtin_amdgcn_exp2f(rw[c2] * L2E); }
        else if (j == 50) { float ebv = __builtin_amdgcn_exp2f(rw[0] * L2E);
                            a = ebv; c = ebv; }
        else              { a = 0.0f; c = 0.0f; }
        ((float2*)(E + ((size_t)b * BROWS + t0 + i) * EROW))[j] = make_float2(a, c);
        A = A2; Bv = B2; C = C2; D = D2;
    }
    for (int off = 32; off; off >>= 1) s += __shfl_down(s, off, 64);
    if (j == 0) red[w] = s;
    __syncthreads();
    if (tid == 0) partials[bid] = (red[0] + red[1]) + (red[2] + red[3]);
}

// ========== K2: recursion — producer/consumer wave split (R16, byte-identical) ==========
extern "C" __global__ void __launch_bounds__(128)
ctc_rec(const int* __restrict__ tgt,
        const int* __restrict__ ilen,
        const int* __restrict__ tlen,
        float* __restrict__ ws,
        float* __restrict__ out)
{
    __shared__ float bufA[32 * EROW];   // 16 KB
    __shared__ float bufB[32 * EROW];   // 16 KB
    unsigned int* cnt = (unsigned int*)ws;
    float* partials = ws + 1;
    float* nlls = ws + 1 + NB1;
    const int b = blockIdx.x;
    const int tid = threadIdx.x;
    const int wav = tid >> 6;
    const int l = tid & 63;
    const float* E = ws + EOFF + (size_t)b * BROWS * EROW;
    const int* tg = tgt + b * S_DIM;
    const int len = ilen[b];
    const int tl  = tlen[b];
    const int steps = len - 1;          // t = 1..len-1 ; len in [400,800]
    const int nfull = steps >> 5;
    const int nst   = steps & 31;
    const int N     = nfull + (nst ? 1 : 0);

#define STAGE_P(BUFP, SB) do { \
    const int tb_ = 1 + 32 * (SB); \
    float* bp_ = (BUFP); \
    _Pragma("unroll") \
    for (int g_ = 0; g_ < 16; ++g_) { \
        gl16(E + (size_t)(tb_ + 2 * g_) * EROW + 4 * l, bp_ + g_ * 256); \
    } \
} while (0)

#define WAIT0 do { \
    asm volatile("s_waitcnt vmcnt(0)" ::: "memory"); \
    __builtin_amdgcn_sched_barrier(0); \
} while (0)

    if (wav == 1) {
        // ---------------- stager wave ----------------
        STAGE_P(bufA, 0); WAIT0;
        __builtin_amdgcn_s_barrier();                // bar#0: buf(0) ready
        #pragma unroll 1
        for (int k = 1; k < N; ++k) {
            STAGE_P((k & 1) ? bufB : bufA, k); WAIT0;
            __builtin_amdgcn_s_barrier();            // bar#k
        }
        return;                                       // exactly N barriers
    }

    // ---------------- consumer wave ----------------
    float cs1f = 0, cs3f = 0;
    if (l <= 49) {
        int v1 = tg[2 * l];
        int vp = (l >= 1) ? tg[2 * l - 1] : -1;
        cs1f = (v1 != vp) ? 1.0f : 0.0f;
        int v3 = tg[2 * l + 1];
        cs3f = (v3 != v1) ? 1.0f : 0.0f;
    }

    float p0 = 0, p1 = 0, p2 = 0, p3 = 0;
    float qv = 0, sff = 0, sfg = 0;
    int   el = 0, eLp = 0;
    {
        float2 q0 = ((const float2*)E)[l];
        float eb0 = rl50(q0.x);
        p0 = (l == 0) ? eb0  : 0.0f;
        p1 = (l == 0) ? q0.x : 0.0f;
    }

    float2 ga0, ga1, ga2, ga3, gb0, gb1, gb2, gb3;

#define PREF_(BUF, G, R0, R1, R2, R3) do { \
    const float2* bp_ = (const float2*)(BUF); \
    R0 = bp_[(4 * (G) + 0) * 64 + l]; \
    R1 = bp_[(4 * (G) + 1) * 64 + l]; \
    R2 = bp_[(4 * (G) + 2) * 64 + l]; \
    R3 = bp_[(4 * (G) + 3) * 64 + l]; \
} while (0)

#define BD do { \
    float mz_ = fmaxf(fmaxf(p0, p1), fmaxf(p2, p3)); \
    int dead_ = (mz_ == 0.0f) ? 1 : 0; \
    int er_ = (int)((__float_as_uint(mz_) >> 23) & 255u); \
    unsigned fld_ = dead_ ? 127u : (unsigned)(254 - er_); \
    float sc_ = __uint_as_float(fld_ << 23); \
    p0 *= sc_; p1 *= sc_; p2 *= sc_; p3 *= sc_; \
    el += dead_ ? 0 : (er_ - 127); \
    int e1s_ = dpp_shr1_i(el); \
    int elA_ = dead_ ? e1s_ : el; \
    int e2s_ = dpp_shr1_i(elA_); \
    int elB_ = dead_ ? e2s_ : el; \
    int e3s_ = dpp_shr1_i(elB_); \
    int d1_ = e3s_ - elB_; d1_ = d1_ < -120 ? -120 : (d1_ > 120 ? 120 : d1_); \
    int d2_ = eLp  - elB_; d2_ = d2_ < -120 ? -120 : (d2_ > 120 ? 120 : d2_); \
    sfg = (l == 0) ? 0.0f : __uint_as_float((unsigned)(d1_ + 127) << 23); \
    sff = (l == 0) ? 0.0f : __uint_as_float((unsigned)(d2_ + 127) << 23); \
    el = elB_; eLp = e3s_; \
} while (0)

#define ST(SF, Q, EBS) do { \
    float h3_ = qv * (SF); \
    float vown_ = fmaf(cs3f, p1, p2 + p3); \
    float n3_ = vown_ * (Q).y; \
    float n0_ = (p0 + h3_) * (EBS); \
    float n1_ = fmaf(cs1f, h3_, p0 + p1) * (Q).x; \
    float n2_ = (p1 + p2) * (EBS); \
    qv = dpp_shr1_f(n3_); \
    p0 = n0_; p1 = n1_; p2 = n2_; p3 = n3_; \
} while (0)

#define GRP_(R0, R1, R2, R3) do { \
    BD; \
    ST(sff, R0, rl50(R0.x)); \
    ST(sfg, R1, rl50(R1.x)); \
    ST(sfg, R2, rl50(R2.x)); \
    ST(sfg, R3, rl50(R3.x)); \
} while (0)

#define GRPT_(R0, R1, R2, R3, BASE) do { \
    if ((BASE) < nst) { \
        BD; \
        ST(sff, R0, rl50(R0.x)); \
        if ((BASE) + 1 < nst) ST(sfg, R1, rl50(R1.x)); \
        if ((BASE) + 2 < nst) ST(sfg, R2, rl50(R2.x)); \
        if ((BASE) + 3 < nst) ST(sfg, R3, rl50(R3.x)); \
    } \
} while (0)

#define CONS_FULL(BUF) do { \
    PREF_(BUF, 0, ga0, ga1, ga2, ga3); \
    PREF_(BUF, 1, gb0, gb1, gb2, gb3); GRP_(ga0, ga1, ga2, ga3); \
    PREF_(BUF, 2, ga0, ga1, ga2, ga3); GRP_(gb0, gb1, gb2, gb3); \
    PREF_(BUF, 3, gb0, gb1, gb2, gb3); GRP_(ga0, ga1, ga2, ga3); \
    PREF_(BUF, 4, ga0, ga1, ga2, ga3); GRP_(gb0, gb1, gb2, gb3); \
    PREF_(BUF, 5, gb0, gb1, gb2, gb3); GRP_(ga0, ga1, ga2, ga3); \
    PREF_(BUF, 6, ga0, ga1, ga2, ga3); GRP_(gb0, gb1, gb2, gb3); \
    PREF_(BUF, 7, gb0, gb1, gb2, gb3); GRP_(ga0, ga1, ga2, ga3); \
    GRP_(gb0, gb1, gb2, gb3); \
} while (0)

#define CONS_TAIL(BUF) do { \
    PREF_(BUF, 0, ga0, ga1, ga2, ga3); \
    PREF_(BUF, 1, gb0, gb1, gb2, gb3); GRPT_(ga0, ga1, ga2, ga3, 0); \
    PREF_(BUF, 2, ga0, ga1, ga2, ga3); GRPT_(gb0, gb1, gb2, gb3, 4); \
    PREF_(BUF, 3, gb0, gb1, gb2, gb3); GRPT_(ga0, ga1, ga2, ga3, 8); \
    PREF_(BUF, 4, ga0, ga1, ga2, ga3); GRPT_(gb0, gb1, gb2, gb3, 12); \
    PREF_(BUF, 5, gb0, gb1, gb2, gb3); GRPT_(ga0, ga1, ga2, ga3, 16); \
    PREF_(BUF, 6, ga0, ga1, ga2, ga3); GRPT_(gb0, gb1, gb2, gb3, 20); \
    PREF_(BUF, 7, gb0, gb1, gb2, gb3); GRPT_(ga0, ga1, ga2, ga3, 24); \
    GRPT_(gb0, gb1, gb2, gb3, 28); \
} while (0)

    __builtin_amdgcn_s_barrier();                    // bar#0: buf(0) ready
    #pragma unroll 1
    for (int k = 0; k + 1 < N; ++k) {
        const float* cur = (k & 1) ? bufB : bufA;
        CONS_FULL(cur);
        __builtin_amdgcn_s_barrier();                // bar#k+1
    }
    {
        const float* cur = ((N - 1) & 1) ? bufB : bufA;
        if (nst) { CONS_TAIL(cur); } else { CONS_FULL(cur); }
    }

    // extract alpha[2*tl] and alpha[2*tl-1]  (log2 domain via p, el)
    int idx = 2 * tl;
    int lanehi = idx >> 2, rhi = idx & 3;
    int lanelo = (idx - 1) >> 2, rlo = (idx - 1) & 3;
    float q0 = __shfl(p0, lanehi, 64), q1 = __shfl(p1, lanehi, 64);
    float q2 = __shfl(p2, lanehi, 64), q3 = __shfl(p3, lanehi, 64);
    int   eh = __shfl(el, lanehi, 64);
    float ph = (rhi == 0) ? q0 : (rhi == 1) ? q1 : (rhi == 2) ? q2 : q3;
    float g0 = __shfl(p0, lanelo, 64), g1 = __shfl(p1, lanelo, 64);
    float g2 = __shfl(p2, lanelo, 64), g3 = __shfl(p3, lanelo, 64);
    int   eo = __shfl(el, lanelo, 64);
    float pl = (rlo == 0) ? g0 : (rlo == 1) ? g1 : (rlo == 2) ? g2 : g3;
    float vhi = (ph > 0.0f) ? __builtin_amdgcn_logf(ph) + (float)eh : -3.0e9f;
    float vlo = (pl > 0.0f) ? __builtin_amdgcn_logf(pl) + (float)eo : -3.0e9f;
    float m = fmaxf(vhi, vlo);
    float d = fminf(vhi, vlo) - m;
    float ll2 = m + __builtin_amdgcn_logf(1.0f + __builtin_amdgcn_exp2f(d));
    float nll = -ll2 * LN2;
    if (!(nll < 1e9f)) nll = 0.0f;      // zero_infinity (NaN-safe)

    int last = 0;
    if (l == 0) {
        nlls[b] = nll;
        __threadfence();
        unsigned old = __hip_atomic_fetch_add(cnt, 1u, __ATOMIC_ACQ_REL,
                                              __HIP_MEMORY_SCOPE_AGENT);
        last = (old == B_DIM - 1) ? 1 : 0;
    }
    last = __shfl(last, 0, 64);
    if (last) {
        float ps = 0.0f;
        for (int i = l; i < NB1; i += 64) ps += partials[i];
        for (int off = 32; off; off >>= 1) ps += __shfl_down(ps, off, 64);
        float cs = 0.0f;
        if (l < B_DIM) cs = nlls[l] / (float)tlen[l];
        for (int off = 32; off; off >>= 1) cs += __shfl_down(cs, off, 64);
        if (l == 0) {
            float smooth = -ps / (float)((long long)T_DIM * B_DIM * V_DIM);
            float ctc = cs / (float)B_DIM;
            out[0] = 0.9f * ctc + 0.1f * smooth;
        }
    }
}

extern "C" void kernel_launch(void* const* d_in, const int* in_sizes, int n_in,
                              void* d_out, int out_size, void* d_ws, size_t ws_size,
                              hipStream_t stream) {
    const float* lp  = (const float*)d_in[0];
    const int* tgt   = (const int*)d_in[1];
    const int* ilen  = (const int*)d_in[2];
    const int* tlen  = (const int*)d_in[3];
    float* out = (float*)d_out;
    float* ws  = (float*)d_ws;
    ctc_prep<<<NB1, 256, 0, stream>>>(lp, tgt, ws);
    ctc_rec<<<B_DIM, 128, 0, stream>>>(tgt, ilen, tlen, ws, out);
}